// Round 13
// baseline (295.738 us; speedup 1.0000x reference)
//
#include <hip/hip_runtime.h>

#define NWIN 1000
#define WIN  500
#define HID  30
#define ANC  7
#define BATCH 64
#define KS   75
#define PADH 37
#define OBASE_ELEMS (BATCH*ANC*NWIN*2)   // 896000

// k1 geometry: 21 chunks of 24 positions (504 padded; 500 real)
#define CK   24
#define NCK  21

// LDS float-offset map (flat array; epilogue overlays the front)
//   xt[buf][12 gran][64 slot][4] : buf*3072 + k*256 + slot*4 + e  [0 .. 6143]
//     slot s holds batch b = (s&15)*4 + (s>>4)  (source-swizzled so compute's
//     16 bq-lanes hit 8 banks 2-way = conflict-free)
//   W [buf][24 pos][32]          : 6144 + buf*768 + p*32 + j      [6144 .. 7679]
//   hs[64 b][61]                 : b*61 + col  (overlay)          [0 .. 3903]
#define XT(buf,k)     ((buf)*3072 + (k)*256)
#define WBASE(buf)    (6144 + (buf)*768)
#define WB(buf,p,j)   (WBASE(buf) + (p)*32 + (j))
#define HS(b,col)     ((b)*61 + (col))

__device__ __forceinline__ void gload_lds16(const float* g, float* l) {
    __builtin_amdgcn_global_load_lds(
        (const __attribute__((address_space(1))) void*)g,
        (__attribute__((address_space(3))) void*)l, 16, 0, 0);
}

// ---------------------------------------------------------------------------
// Kernel 1 (v11): zero staging registers (x AND W via global_load_lds; only
// acc[32] lives across the loop) with REQUEST-EFFICIENT x staging:
// v10 used 48 gload_lds4/chunk (64 scattered lines each -> ~3072 L2 requests
// per chunk-block, drained every barrier). v11 uses 12 gload_lds16 into
// xt[k][slot][4] (per-lane granule = one batch's 2pos x 2ch float4; adjacent
// granules share 64B lines -> 4x fewer requests, full-line HBM efficiency).
// Compute reads x as dword pairs (+0/+8B = its channel's 2 positions) from a
// batch-swizzled slot order -> 2-way bank aliasing only (free).
// wave = (ch, ph); lane = (bq 0..15, jq 0..3): acc[4 b][8 j].
// ---------------------------------------------------------------------------
__global__ __launch_bounds__(256, 4) void k1(
        const float* __restrict__ x,
        const float* __restrict__ W1, const float* __restrict__ b1,
        const float* __restrict__ W2, const float* __restrict__ b2,
        float* __restrict__ out_base)
{
    __shared__ float smem[7680];   // 30,720 B

    const int n    = blockIdx.x;
    const int t    = threadIdx.x;
    const int wid  = __builtin_amdgcn_readfirstlane(t >> 6);
    const int lane = t & 63;
    const int ch   = wid & 1;          // channel
    const int ph   = wid >> 1;         // position half (12 each)
    const int bq   = lane & 15;
    const int jq   = lane >> 4;
    const int b0   = bq * 4;
    const int j0   = jq * 8;

    float acc[4][8];
#pragma unroll
    for (int i = 0; i < 4; ++i)
#pragma unroll
        for (int j = 0; j < 8; ++j) acc[i][j] = 0.f;

    const float4* __restrict__ x4 = reinterpret_cast<const float4*>(x);
    // staging batch for this lane (slot=lane holds batch sb)
    const int sb = ((lane & 15) << 2) + (lane >> 4);
    const float4* __restrict__ gxs = x4 + (size_t)sb * 250000u + (size_t)n * 250u;
    const float* __restrict__ gw = W1 + (size_t)n * 15000u;

    // x staging: 12 gload_lds16 per chunk, 3 per wave. Granule k covers chunk
    // positions 2k, 2k+1 (both channels) for slot-batch sb.
    auto issue_x = [&](int ck, int buf) {
#pragma unroll
        for (int r = 0; r < 3; ++r) {
            const int k = wid * 3 + r;          // wave-uniform 0..11
            int gq = ck * 12 + k;               // float4 index in window row
            if (gq > 249) gq = 249;             // tail clamp (W rows zeroed)
            gload_lds16((const float*)(gxs + gq), &smem[XT(buf, k)]);
        }
    };

    // W staging: 24 rows x 30 floats -> 192 16B granules into padded [24][32].
    // Row clamp only; row straddle (floats 30,31) lands in pad slots.
    auto issue_w = [&](int ck, int buf) {
        if (t < 192) {
            int gp = ck * CK + (t >> 3);
            if (gp > 499) gp = 499;
            const size_t off = (size_t)gp * 30u + (size_t)(t & 7) * 4u;  // <= 14998
            gload_lds16(gw + off, &smem[WBASE(buf) + (t & 192) * 4]);
        }
    };

    // ---- prologue ------------------------------------------------------
    issue_w(0, 0);
    issue_x(0, 0);
    __syncthreads();   // drains vmcnt before barrier -> buf0 ready

    // ---- main loop: 1 barrier per chunk --------------------------------
    for (int ck = 0; ck < NCK; ++ck) {
        const int cur = ck & 1, nxt = cur ^ 1;
        const bool pre = (ck < NCK - 1);
        if (pre) {
            issue_w(ck + 1, nxt);
            issue_x(ck + 1, nxt);
        }
        if (ck == NCK - 1) {
            // zero W rows 20..23 (= positions 500..503) of this buffer
            if (t < 128) smem[WBASE(cur) + 640 + t] = 0.f;
            __syncthreads();
        }

#pragma unroll
        for (int i = 0; i < 6; ++i) {
            const int g  = ph * 6 + i;          // granule index
            const int p0 = 2 * g, p1 = 2 * g + 1;
            // x: batch b0+ii lives at slot bq + ii*16; channel ch at dwords
            // +0 (pos p0) and +2 (pos p1) -> ds_read2_b32-shaped pair.
            float xa[4], xb[4];
#pragma unroll
            for (int ii = 0; ii < 4; ++ii) {
                const float* xg = &smem[XT(cur, g) + (bq + ii * 16) * 4 + ch];
                xa[ii] = fmaf(2.f, xg[0], -1.f);
                xb[ii] = fmaf(2.f, xg[2], -1.f);
            }
            {
                const float4 w0 = *reinterpret_cast<const float4*>(&smem[WB(cur, p0, j0)]);
                const float4 w1 = *reinterpret_cast<const float4*>(&smem[WB(cur, p0, j0 + 4)]);
                const float wv[8] = {w0.x, w0.y, w0.z, w0.w, w1.x, w1.y, w1.z, w1.w};
#pragma unroll
                for (int ii = 0; ii < 4; ++ii)
#pragma unroll
                    for (int jj = 0; jj < 8; ++jj)
                        acc[ii][jj] = fmaf(xa[ii], wv[jj], acc[ii][jj]);
            }
            {
                const float4 w2 = *reinterpret_cast<const float4*>(&smem[WB(cur, p1, j0)]);
                const float4 w3 = *reinterpret_cast<const float4*>(&smem[WB(cur, p1, j0 + 4)]);
                const float wv[8] = {w2.x, w2.y, w2.z, w2.w, w3.x, w3.y, w3.z, w3.w};
#pragma unroll
                for (int ii = 0; ii < 4; ++ii)
#pragma unroll
                    for (int jj = 0; jj < 8; ++jj)
                        acc[ii][jj] = fmaf(xb[ii], wv[jj], acc[ii][jj]);
            }
        }

        __syncthreads();   // drains this iter's gload_lds; publishes nxt
    }

    // ---- epilogue: reduce the two ph-halves into hs ---------------------
    if (ph == 0) {
#pragma unroll
        for (int ii = 0; ii < 4; ++ii)
#pragma unroll
            for (int jj = 0; jj < 8; ++jj) {
                const int j = j0 + jj;
                if (j < 30) smem[HS(b0 + ii, ch * 30 + j)] = acc[ii][jj];
            }
    }
    __syncthreads();
    if (ph == 1) {
#pragma unroll
        for (int ii = 0; ii < 4; ++ii)
#pragma unroll
            for (int jj = 0; jj < 8; ++jj) {
                const int j = j0 + jj;
                if (j < 30) smem[HS(b0 + ii, ch * 30 + j)] += acc[ii][jj];
            }
    }
    __syncthreads();

    {   // bias + relu + two-pass batch stats (64-lane butterflies) + normalize
        const int bb = t & 63;
        const int q2 = t >> 6;
        const int c2 = q2 >> 1;
        const int jh = (q2 & 1) * 15;
        const float* __restrict__ b1p = b1 + n * HID + jh;
#pragma unroll
        for (int jj = 0; jj < 15; ++jj) {
            const int col = c2 * 30 + jh + jj;
            float v = smem[HS(bb, col)] + b1p[jj];
            v = fmaxf(v, 0.f);
            float s = v;
#pragma unroll
            for (int off = 32; off > 0; off >>= 1) s += __shfl_xor(s, off);
            const float mean = s * (1.f / 64.f);
            const float d = v - mean;
            float ss = d * d;
#pragma unroll
            for (int off = 32; off > 0; off >>= 1) ss += __shfl_xor(ss, off);
            const float var = ss * (1.f / 64.f);
            const float rn  = rsqrtf(var + 1e-5f);
            smem[HS(bb, col)] = d * rn;
        }
    }
    __syncthreads();

    // ---- GEMM2 + write out_base[b][a][n][c] -----------------------------
    const float* __restrict__ w2p = W2 + (size_t)n * (HID * ANC);
    float2* __restrict__ ob2 = reinterpret_cast<float2*>(out_base);
    for (int idx = t; idx < BATCH * ANC; idx += 256) {
        const int bb = idx / 7, a = idx - bb * 7;
        float o0 = b2[n * ANC + a], o1 = o0;
#pragma unroll
        for (int h = 0; h < HID; ++h) {
            const float wv = w2p[h * ANC + a];
            o0 = fmaf(smem[HS(bb, h)],      wv, o0);
            o1 = fmaf(smem[HS(bb, 30 + h)], wv, o1);
        }
        ob2[((size_t)bb * ANC + a) * NWIN + n] = make_float2(o0, o1);
    }
}

// ---------------------------------------------------------------------------
// Kernel 2: softmax over ANC + reflect-pad + conv (2 needed output columns)
// via sum/diff factorization. (256,2): 112-reg budget, no spill.
// ---------------------------------------------------------------------------
__global__ __launch_bounds__(256, 2) void k2(
        const float* __restrict__ out_base,
        const float* __restrict__ conv_w, const float* __restrict__ conv_b,
        float* __restrict__ out_smooth)
{
    __shared__ float2 sdl[199 * ANC];
    __shared__ float2 wael[ANC * ANC * KS];

    const int bidx = blockIdx.x;
    const int b  = bidx >> 3;
    const int ht = bidx & 7;
    const int h0 = ht * 125;
    const int t  = threadIdx.x;

    const float2* __restrict__ cw2 = reinterpret_cast<const float2*>(conv_w);
    for (int idx = t; idx < ANC * ANC * KS; idx += 256) {
        const float2 w = cw2[idx];
        wael[idx] = make_float2(w.x + w.y, w.x - w.y);
    }

    if (t < 199) {
        const int hglob = h0 - PADH + t;
        const int hm = hglob < 0 ? -hglob
                     : (hglob >= NWIN ? 2 * NWIN - 2 - hglob : hglob);
        float p[2][ANC];
#pragma unroll
        for (int c = 0; c < 2; ++c) {
            float v[ANC];
            float m = -1e30f;
#pragma unroll
            for (int a = 0; a < ANC; ++a) {
                v[a] = out_base[(((size_t)b * ANC + a) * NWIN + hm) * 2 + c];
                m = fmaxf(m, v[a]);
            }
            float s = 0.f;
#pragma unroll
            for (int a = 0; a < ANC; ++a) { v[a] = __expf(v[a] - m); s += v[a]; }
            const float inv = 1.f / s;
#pragma unroll
            for (int a = 0; a < ANC; ++a) p[c][a] = v[a] * inv;
        }
#pragma unroll
        for (int a = 0; a < ANC; ++a)
            sdl[t * ANC + a] = make_float2(p[0][a] + p[1][a], p[0][a] - p[1][a]);
    }
    __syncthreads();

    for (int idx = t; idx < ANC * 125; idx += 256) {
        const int o  = idx / 125;
        const int hl = idx % 125;
        float sa = 0.f, de = 0.f;
        const float2* __restrict__ wrow = &wael[o * ANC * KS];
#pragma unroll 1
        for (int i = 0; i < ANC; ++i) {
            const float2* __restrict__ sdp = &sdl[hl * ANC + i];
            const float2* __restrict__ wp  = &wrow[i * KS];
#pragma unroll 5
            for (int kh = 0; kh < KS; ++kh) {
                const float2 sd = sdp[kh * ANC];
                const float2 we = wp[kh];
                sa = fmaf(sd.x, we.x, sa);
                de = fmaf(sd.y, we.y, de);
            }
        }
        const float cb = conv_b[o];
        const float o0 = 0.5f * (sa - de) + cb;
        const float o1 = 0.5f * (sa + de) + cb;
        const size_t base = (((size_t)b * ANC + o) * NWIN + (h0 + hl)) * 2;
        out_smooth[base + 0] = o0;
        out_smooth[base + 1] = o1;
    }
}

extern "C" void kernel_launch(void* const* d_in, const int* in_sizes, int n_in,
                              void* d_out, int out_size, void* d_ws, size_t ws_size,
                              hipStream_t stream)
{
    const float* x      = (const float*)d_in[0];
    const float* W1     = (const float*)d_in[1];
    const float* b1     = (const float*)d_in[2];
    const float* W2     = (const float*)d_in[3];
    const float* b2     = (const float*)d_in[4];
    const float* conv_w = (const float*)d_in[5];
    const float* conv_b = (const float*)d_in[6];
    float* out = (float*)d_out;

    k1<<<dim3(NWIN), dim3(256), 0, stream>>>(x, W1, b1, W2, b2, out);
    k2<<<dim3(BATCH * 8), dim3(256), 0, stream>>>(out, conv_w, conv_b,
                                                  out + OBASE_ELEMS);
}